// Round 4
// baseline (691.060 us; speedup 1.0000x reference)
//
#include <hip/hip_runtime.h>
#include <stdint.h>

#define NE 50000   // entities
#define DD 128     // dim
#define RR 16      // relations
#define EE 50000   // edges per relation
#define NT 128     // node tile per block
#define NTOT (RR * NE)                 // 800000 flat (n,r) keys, node-major
#define SCAN_BLK 4096
#define NSCAN ((NTOT + SCAN_BLK - 1) / SCAN_BLK)   // 196

typedef short  shortx8 __attribute__((ext_vector_type(8)));
typedef short  shortx4 __attribute__((ext_vector_type(4)));
typedef float  floatx4 __attribute__((ext_vector_type(4)));

__device__ __forceinline__ unsigned short f2bf(float f) {
    unsigned u = __float_as_uint(f);
    u += 0x7fffu + ((u >> 16) & 1u);   // RNE
    return (unsigned short)(u >> 16);
}
__device__ __forceinline__ float bf2f(unsigned short h) {
    return __uint_as_float(((unsigned)h) << 16);
}

__device__ __forceinline__ void lds_dma16(const void* g, void* l) {
    __builtin_amdgcn_global_load_lds(
        (const __attribute__((address_space(1))) unsigned int*)g,
        (__attribute__((address_space(3))) unsigned int*)l, 16, 0, 0);
}

// ---- fused init: zero counts | rel_trans -> MFMA-fragment-ordered bf16 Tf | ent_emb -> bf16
// Tf layout: element T[r][row][k] at ((((r*8+(row>>4))*4+(k>>5))*64) + ((k>>3)&3)*16 + (row&15))*8 + (k&7)
// so a wave's A-frag (r, rowgrp rg, kt) is a lane-coalesced 1KB chunk: base + lane*16B.
#define ZB 782
#define TB 128
#define EB 6250
__global__ void prep_k(const float* __restrict__ rt, unsigned short* __restrict__ Tf,
                       const float4* __restrict__ emb, shortx4* __restrict__ embA,
                       int* __restrict__ counts) {
    int b = blockIdx.x, t = threadIdx.x;
    if (b < ZB) {
        int i4 = b * 256 + t;
        if (i4 < NTOT / 4) *(int4*)(counts + i4 * 4) = make_int4(0, 0, 0, 0);
    } else if (b < ZB + TB) {
        int c = (b - ZB) * 256 + t;          // chunk: 8 consecutive k of one (r,row)
        int r = c >> 11, row = (c >> 4) & 127, cb = c & 15;
        int kt = cb >> 2, qq = cb & 3, rg = row >> 4, m = row & 15;
        const float4* src = (const float4*)(rt + (size_t)c * 8);
        float4 v0 = src[0], v1 = src[1];
        shortx8 w;
        w[0] = (short)f2bf(v0.x); w[1] = (short)f2bf(v0.y);
        w[2] = (short)f2bf(v0.z); w[3] = (short)f2bf(v0.w);
        w[4] = (short)f2bf(v1.x); w[5] = (short)f2bf(v1.y);
        w[6] = (short)f2bf(v1.z); w[7] = (short)f2bf(v1.w);
        size_t idx = ((((size_t)r * 8 + rg) * 4 + kt) * 64 + qq * 16 + m) * 8;
        *(shortx8*)(Tf + idx) = w;
    } else {
        int i = (b - ZB - TB) * 256 + t;
        if (i < NE * DD / 4) {
            float4 v = emb[i];
            shortx4 w;
            w[0] = (short)f2bf(v.x); w[1] = (short)f2bf(v.y);
            w[2] = (short)f2bf(v.z); w[3] = (short)f2bf(v.w);
            embA[i] = w;
        }
    }
}

// key = node*RR + r  (node-major). blockIdx.y = relation.
__global__ void hist_k(const int* __restrict__ erow, int* __restrict__ counts) {
    int r  = blockIdx.y;
    int i4 = blockIdx.x * 256 + threadIdx.x;
    if (i4 < EE / 4) {
        int4 rw = *(const int4*)(erow + (size_t)r * EE + i4 * 4);
        atomicAdd(&counts[rw.x * RR + r], 1);
        atomicAdd(&counts[rw.y * RR + r], 1);
        atomicAdd(&counts[rw.z * RR + r], 1);
        atomicAdd(&counts[rw.w * RR + r], 1);
    }
}

__global__ void scanA(const int* __restrict__ c, int* __restrict__ bsum) {
    int b = blockIdx.x, t = threadIdx.x;
    int base = b * SCAN_BLK + t * 16;
    int s = 0;
    #pragma unroll
    for (int i = 0; i < 16; i++) {
        int idx = base + i;
        if (idx < NTOT) s += c[idx];
    }
    __shared__ int sh[256];
    sh[t] = s;
    __syncthreads();
    for (int off = 128; off > 0; off >>= 1) {
        if (t < off) sh[t] += sh[t + off];
        __syncthreads();
    }
    if (t == 0) bsum[b] = sh[0];
}

// scanC also derives its own block prefix from raw bsum (scanB folded in).
__global__ void scanC(int* __restrict__ counts, int* __restrict__ rp,
                      const int* __restrict__ bsum) {
    int b = blockIdx.x, t = threadIdx.x;
    __shared__ int shb[256];
    shb[t] = (t < NSCAN) ? bsum[t] : 0;
    __syncthreads();
    {   // inclusive scan of shb
        for (int off = 1; off < 256; off <<= 1) {
            int add = (t >= off) ? shb[t - off] : 0;
            __syncthreads();
            shb[t] += add;
            __syncthreads();
        }
    }
    int blockPrefix = (b > 0) ? shb[b - 1] : 0;
    int base = b * SCAN_BLK + t * 16;
    int vals[16];
    int s = 0;
    #pragma unroll
    for (int i = 0; i < 16; i++) {
        int idx = base + i;
        vals[i] = (idx < NTOT) ? counts[idx] : 0;
        s += vals[i];
    }
    __shared__ int sh[256];
    sh[t] = s;
    __syncthreads();
    for (int off = 1; off < 256; off <<= 1) {
        int add = (t >= off) ? sh[t - off] : 0;
        __syncthreads();
        sh[t] += add;
        __syncthreads();
    }
    int run = blockPrefix + sh[t] - s;
    #pragma unroll
    for (int i = 0; i < 16; i++) {
        int idx = base + i;
        if (idx < NTOT) {
            int cv = vals[i];
            rp[idx]     = run;
            counts[idx] = run;   // cursor for fill_k
            run += cv;
            if (idx == NTOT - 1) rp[NTOT] = run;
        }
    }
}

__global__ void fill_k(const int* __restrict__ erow, const int* __restrict__ ecol,
                       const float* __restrict__ eval, int* __restrict__ cursor,
                       int2* __restrict__ edges) {
    int r  = blockIdx.y;
    int i4 = blockIdx.x * 256 + threadIdx.x;
    if (i4 < EE / 4) {
        int4   rw = *(const int4*)(erow + (size_t)r * EE + i4 * 4);
        int4   cl = *(const int4*)(ecol + (size_t)r * EE + i4 * 4);
        float4 vl = *(const float4*)(eval + (size_t)r * EE + i4 * 4);
        int p;
        p = atomicAdd(&cursor[rw.x * RR + r], 1); edges[p] = make_int2(cl.x, __float_as_int(vl.x));
        p = atomicAdd(&cursor[rw.y * RR + r], 1); edges[p] = make_int2(cl.y, __float_as_int(vl.y));
        p = atomicAdd(&cursor[rw.z * RR + r], 1); edges[p] = make_int2(cl.z, __float_as_int(vl.z));
        p = atomicAdd(&cursor[rw.w * RR + r], 1); edges[p] = make_int2(cl.w, __float_as_int(vl.w));
    }
}

__device__ __forceinline__ void accum_chunks(float a0[8], float a1[8], float v,
                                             shortx8 c0, shortx8 c1) {
    #pragma unroll
    for (int j = 0; j < 8; j++) {
        a0[j] = fmaf(v, bf2f((unsigned short)c0[j]), a0[j]);
        a1[j] = fmaf(v, bf2f((unsigned short)c1[j]), a1[j]);
    }
}

// Fused layer, LDS-pipelined:
//  phase1(r): consume Sg(edge0)+eb1(edge1)+tail -> pack -> Bt; stage A-frags kt0/1 (global, L2)
//  barrier
//  phase3(r): DMA Sg<-edge0(r+1) [global_load_lds, per-lane addr]; eb1<-edge1(r+1);
//             meta(r+2); MFMA kt0..3 with kt2/3 staged mid-stream
//  barrier
// Wave tile 64i x 32n: acc[4][2], A-frags from global Tf (no At in LDS).
template<bool FINAL>
__global__ __launch_bounds__(512, 4)
void layer_k(const unsigned short* __restrict__ embIn,
             const unsigned short* __restrict__ Tf,
             const int* __restrict__ rp,
             const int2* __restrict__ eg,
             unsigned short* __restrict__ embOut,
             float* __restrict__ outF)
{
    __shared__ __align__(16) unsigned short Bt[128 * 128];     // 32 KB
    __shared__ __align__(16) unsigned short Sg[2 * 2 * 512 * 8]; // 32 KB edge0 staging
    __shared__ float ssred[2][128];

    const int t    = threadIdx.x;
    const int lane = t & 63;
    const int w    = t >> 6;
    const int wi2  = w & 1;       // i half (x64)
    const int wn2  = w >> 1;      // n quarter (x32)
    const int colq = lane & 15;
    const int q    = lane >> 4;
    const int n0   = blockIdx.x * NT;
    const int nsub = t >> 3;      // node within pass (0..63)
    const int dgrp = t & 7;       // dim chunks dgrp, dgrp+8

    const int nn[2] = { n0 + nsub, n0 + 64 + nsub };

    floatx4 acc[4][2];
    #pragma unroll
    for (int a = 0; a < 4; a++)
        #pragma unroll
        for (int c = 0; c < 2; c++)
            acc[a][c] = (floatx4){0.f, 0.f, 0.f, 0.f};

    auto loadMeta = [&](int r, int p, int& s, int& c, int2& E0, int2& E1) {
        int n  = nn[p];
        bool ok = n < NE;
        int key = (ok ? n : 0) * RR + r;
        int a = rp[key], b2 = rp[key + 1];
        s = a; c = ok ? (b2 - a) : 0;
        E0 = eg[s];      // edges array padded; clamped at use
        E1 = eg[s + 1];
    };
    auto tfrag = [&](int r, int it2, int kt) -> shortx8 {
        size_t idx = ((((size_t)r * 8 + (wi2 * 4 + it2)) * 4 + kt) * 64 + lane) * 8;
        return *(const shortx8*)(Tf + idx);
    };

    // ---- prologue: meta(0) -> DMA Sg(0), eb1(0); meta(1)
    int   sC[2], cC[2];  float v0C[2], v1C[2];
    int   sN[2], cN[2];  int2  e0N[2], e1N[2];
    shortx8 eb1[2][2];
    #pragma unroll
    for (int p = 0; p < 2; p++) {
        int2 E0, E1;
        loadMeta(0, p, sC[p], cC[p], E0, E1);
        int col0 = cC[p] > 0 ? E0.x : 0;
        int col1 = cC[p] > 1 ? E1.x : 0;
        v0C[p] = cC[p] > 0 ? __int_as_float(E0.y) : 0.f;
        v1C[p] = cC[p] > 1 ? __int_as_float(E1.y) : 0.f;
        const unsigned short* r0 = embIn + (size_t)col0 * DD + dgrp * 8;
        lds_dma16(r0,      &Sg[((p * 2 + 0) * 512 + t) * 8]);
        lds_dma16(r0 + 64, &Sg[((p * 2 + 1) * 512 + t) * 8]);
        const unsigned short* r1 = embIn + (size_t)col1 * DD + dgrp * 8;
        eb1[p][0] = *(const shortx8*)r1;
        eb1[p][1] = *(const shortx8*)(r1 + 64);
    }
    #pragma unroll
    for (int p = 0; p < 2; p++) loadMeta(1, p, sN[p], cN[p], e0N[p], e1N[p]);
    __syncthreads();   // Sg(0) + eb1(0) resident

    #pragma unroll 1
    for (int r = 0; r < RR; r++) {
        // ---- phase 1: stage A-frags kt0/1; consume -> Bt
        shortx8 afA[4], afB[4];
        #pragma unroll
        for (int it2 = 0; it2 < 4; it2++) afA[it2] = tfrag(r, it2, 0);
        #pragma unroll
        for (int it2 = 0; it2 < 4; it2++) afB[it2] = tfrag(r, it2, 1);

        #pragma unroll
        for (int p = 0; p < 2; p++) {
            float a0[8], a1[8];
            #pragma unroll
            for (int j = 0; j < 8; j++) { a0[j] = 0.f; a1[j] = 0.f; }
            shortx8 s0 = *(const shortx8*)&Sg[((p * 2 + 0) * 512 + t) * 8];
            shortx8 s1 = *(const shortx8*)&Sg[((p * 2 + 1) * 512 + t) * 8];
            accum_chunks(a0, a1, v0C[p], s0, s1);
            accum_chunks(a0, a1, v1C[p], eb1[p][0], eb1[p][1]);
            if (cC[p] > 2) {
                #pragma unroll 1
                for (int k = sC[p] + 2; k < sC[p] + cC[p]; k++) {
                    int2 E = eg[k];
                    float v = __int_as_float(E.y);
                    const unsigned short* rw_ = embIn + (size_t)E.x * DD + dgrp * 8;
                    accum_chunks(a0, a1, v, *(const shortx8*)rw_, *(const shortx8*)(rw_ + 64));
                }
            }
            int nl = p * 64 + nsub;
            shortx8 w0, w1;
            #pragma unroll
            for (int j = 0; j < 8; j++) { w0[j] = (short)f2bf(a0[j]); w1[j] = (short)f2bf(a1[j]); }
            int pcA = (dgrp ^ nl) & 7;
            *(shortx8*)&Bt[nl * 128 + pcA * 8] = w0;
            *(shortx8*)&Bt[nl * 128 + (8 | pcA) * 8] = w1;
        }
        __syncthreads();   // Bt(r) ready; Sg free for refill

        // ---- phase 3: DMA Sg(r+1), eb1(r+1), meta(r+2), MFMA(r)
        if (r + 1 < RR) {
            #pragma unroll
            for (int p = 0; p < 2; p++) {
                int col0 = cN[p] > 0 ? e0N[p].x : 0;
                int col1 = cN[p] > 1 ? e1N[p].x : 0;
                v0C[p] = cN[p] > 0 ? __int_as_float(e0N[p].y) : 0.f;
                v1C[p] = cN[p] > 1 ? __int_as_float(e1N[p].y) : 0.f;
                const unsigned short* r0 = embIn + (size_t)col0 * DD + dgrp * 8;
                lds_dma16(r0,      &Sg[((p * 2 + 0) * 512 + t) * 8]);
                lds_dma16(r0 + 64, &Sg[((p * 2 + 1) * 512 + t) * 8]);
                const unsigned short* r1 = embIn + (size_t)col1 * DD + dgrp * 8;
                eb1[p][0] = *(const shortx8*)r1;
                eb1[p][1] = *(const shortx8*)(r1 + 64);
                sC[p] = sN[p]; cC[p] = cN[p];
            }
        }
        if (r + 2 < RR) {
            #pragma unroll
            for (int p = 0; p < 2; p++) loadMeta(r + 2, p, sN[p], cN[p], e0N[p], e1N[p]);
        }

        // MFMA: kt0 (afA), stage kt2; kt1 (afB), stage kt3; kt2; kt3
        shortx8 afC[4], afD[4];
        {
            #pragma unroll
            for (int kt = 0; kt < 4; kt++) {
                int lc = kt * 4 + q;
                shortx8 bfr[2];
                #pragma unroll
                for (int c = 0; c < 2; c++) {
                    int nl = wn2 * 32 + c * 16 + colq;
                    int pc = (lc & 8) | ((lc ^ nl) & 7);
                    bfr[c] = *(const shortx8*)&Bt[nl * 128 + pc * 8];
                }
                const shortx8* af = (kt == 0) ? afA : (kt == 1) ? afB : (kt == 2) ? afC : afD;
                #pragma unroll
                for (int it2 = 0; it2 < 4; it2++)
                    #pragma unroll
                    for (int c = 0; c < 2; c++)
                        acc[it2][c] = __builtin_amdgcn_mfma_f32_16x16x32_bf16(af[it2], bfr[c], acc[it2][c], 0, 0, 0);
                if (kt == 0) {
                    #pragma unroll
                    for (int it2 = 0; it2 < 4; it2++) afC[it2] = tfrag(r, it2, 2);
                } else if (kt == 1) {
                    #pragma unroll
                    for (int it2 = 0; it2 < 4; it2++) afD[it2] = tfrag(r, it2, 3);
                }
            }
        }
        __syncthreads();   // drains Sg DMA + eb1; MFMA done with Bt
    }

    // ---- epilogue. D: col=lane&15 -> n, row=q*4+g -> i (within 16x16 tile)
    if (!FINAL) {
        #pragma unroll
        for (int c = 0; c < 2; c++) {
            int n = n0 + wn2 * 32 + c * 16 + colq;
            if (n < NE) {
                #pragma unroll
                for (int it2 = 0; it2 < 4; it2++) {
                    shortx4 wv;
                    #pragma unroll
                    for (int g = 0; g < 4; g++) {
                        float v = acc[it2][c][g];
                        v = v > 0.f ? v : 0.f;
                        wv[g] = (short)f2bf(v);
                    }
                    *(shortx4*)(embOut + ((size_t)n * DD + wi2 * 64 + it2 * 16 + q * 4)) = wv;
                }
            }
        }
    } else {
        float ssc[2];
        #pragma unroll
        for (int c = 0; c < 2; c++) {
            float ss = 0.f;
            #pragma unroll
            for (int it2 = 0; it2 < 4; it2++)
                #pragma unroll
                for (int g = 0; g < 4; g++) {
                    float v = acc[it2][c][g];
                    v = v > 0.f ? v : 0.f;
                    acc[it2][c][g] = v;
                    ss += v * v;
                }
            ss += __shfl_xor(ss, 16, 64);   // reduce over q quads
            ss += __shfl_xor(ss, 32, 64);
            ssc[c] = ss;
        }
        if (q == 0) {
            #pragma unroll
            for (int c = 0; c < 2; c++)
                ssred[wi2][wn2 * 32 + c * 16 + colq] = ssc[c];
        }
        __syncthreads();
        #pragma unroll
        for (int c = 0; c < 2; c++) {
            int nl = wn2 * 32 + c * 16 + colq;
            float tot = ssred[0][nl] + ssred[1][nl];
            float scale = 1.f / fmaxf(sqrtf(tot), 1e-12f);
            int n = n0 + nl;
            if (n < NE) {
                #pragma unroll
                for (int it2 = 0; it2 < 4; it2++) {
                    floatx4 v4;
                    #pragma unroll
                    for (int g = 0; g < 4; g++) v4[g] = acc[it2][c][g] * scale;
                    *(floatx4*)(outF + ((size_t)n * DD + wi2 * 64 + it2 * 16 + q * 4)) = v4;
                }
            }
        }
    }
}

static inline size_t align256(size_t x) { return (x + 255) & ~(size_t)255; }

extern "C" void kernel_launch(void* const* d_in, const int* in_sizes, int n_in,
                              void* d_out, int out_size, void* d_ws, size_t ws_size,
                              hipStream_t stream)
{
    const float* ent_emb   = (const float*)d_in[0];   // [NE, DD] fp32
    const float* rel_trans = (const float*)d_in[1];   // [RR, DD, DD] fp32
    const float* edge_val  = (const float*)d_in[2];   // [RR, EE] fp32
    const int*   edge_row  = (const int*)d_in[3];     // [RR, EE] int32
    const int*   edge_col  = (const int*)d_in[4];     // [RR, EE] int32
    float* out = (float*)d_out;                       // [NE, DD] fp32

    char* ws = (char*)d_ws;
    size_t off = 0;
    int* counts = (int*)(ws + off);  off = align256(off + (size_t)NTOT * 4);        // hist -> cursor
    int* rpf    = (int*)(ws + off);  off = align256(off + ((size_t)NTOT + 1) * 4);  // node-major row_ptr
    int* bsum   = (int*)(ws + off);  off = align256(off + 256 * 4);
    int2* edges = (int2*)(ws + off); off = align256(off + ((size_t)NTOT + 4) * 8);  // +pad for unguarded e1
    unsigned short* Tf   = (unsigned short*)(ws + off); off = align256(off + (size_t)RR * DD * DD * 2);
    unsigned short* embA = (unsigned short*)(ws + off); off = align256(off + (size_t)NE * DD * 2);
    unsigned short* embB = (unsigned short*)(ws + off); off = align256(off + (size_t)NE * DD * 2);
    // total ~39 MB

    prep_k<<<ZB + TB + EB, 256, 0, stream>>>(rel_trans, Tf, (const float4*)ent_emb,
                                             (shortx4*)embA, counts);
    dim3 eg_grid((EE / 4 + 255) / 256, RR);
    hist_k<<<eg_grid, 256, 0, stream>>>(edge_row, counts);
    scanA<<<NSCAN, 256, 0, stream>>>(counts, bsum);
    scanC<<<NSCAN, 256, 0, stream>>>(counts, rpf, bsum);
    fill_k<<<eg_grid, 256, 0, stream>>>(edge_row, edge_col, edge_val, counts, edges);

    int nb = (NE + NT - 1) / NT;  // 391
    layer_k<false><<<nb, 512, 0, stream>>>(embA, Tf, rpf, edges, embB, nullptr);
    layer_k<true ><<<nb, 512, 0, stream>>>(embB, Tf, rpf, edges, nullptr, out);
}

// Round 5
// 328.885 us; speedup vs baseline: 2.1012x; 2.1012x over previous
//
#include <hip/hip_runtime.h>
#include <stdint.h>

#define NE 50000   // entities
#define DD 128     // dim
#define RR 16      // relations
#define EE 50000   // edges per relation
#define NT 64      // node tile per block
#define NTOT (RR * NE)                 // 800000 flat (n,r) keys, node-major
#define SCAN_BLK 4096
#define NSCAN ((NTOT + SCAN_BLK - 1) / SCAN_BLK)   // 196

typedef short  shortx8 __attribute__((ext_vector_type(8)));
typedef short  shortx4 __attribute__((ext_vector_type(4)));
typedef float  floatx4 __attribute__((ext_vector_type(4)));

__device__ __forceinline__ unsigned short f2bf(float f) {
    unsigned u = __float_as_uint(f);
    u += 0x7fffu + ((u >> 16) & 1u);   // RNE
    return (unsigned short)(u >> 16);
}
__device__ __forceinline__ float bf2f(unsigned short h) {
    return __uint_as_float(((unsigned)h) << 16);
}

// ---- fused init: zero counts | rel_trans -> MFMA-fragment-ordered bf16 Tf | ent_emb -> bf16
// Tf: element T[r][row][k] at ((((r*8+(row>>4))*4+(k>>5))*64) + ((k>>3)&3)*16 + (row&15))*8 + (k&7)
// => wave A-frag (r, rowgrp rg, kt) is one lane-coalesced 1KB chunk: base + lane*16B.
#define ZB 782
#define TB 128
#define EB 6250
__global__ void prep_k(const float* __restrict__ rt, unsigned short* __restrict__ Tf,
                       const float4* __restrict__ emb, shortx4* __restrict__ embA,
                       int* __restrict__ counts) {
    int b = blockIdx.x, t = threadIdx.x;
    if (b < ZB) {
        int i4 = b * 256 + t;
        if (i4 < NTOT / 4) *(int4*)(counts + i4 * 4) = make_int4(0, 0, 0, 0);
    } else if (b < ZB + TB) {
        int c = (b - ZB) * 256 + t;          // chunk: 8 consecutive k of one (r,row)
        int r = c >> 11, row = (c >> 4) & 127, cb = c & 15;
        int kt = cb >> 2, qq = cb & 3, rg = row >> 4, m = row & 15;
        const float4* src = (const float4*)(rt + (size_t)c * 8);
        float4 v0 = src[0], v1 = src[1];
        shortx8 w;
        w[0] = (short)f2bf(v0.x); w[1] = (short)f2bf(v0.y);
        w[2] = (short)f2bf(v0.z); w[3] = (short)f2bf(v0.w);
        w[4] = (short)f2bf(v1.x); w[5] = (short)f2bf(v1.y);
        w[6] = (short)f2bf(v1.z); w[7] = (short)f2bf(v1.w);
        size_t idx = ((((size_t)r * 8 + rg) * 4 + kt) * 64 + qq * 16 + m) * 8;
        *(shortx8*)(Tf + idx) = w;
    } else {
        int i = (b - ZB - TB) * 256 + t;
        if (i < NE * DD / 4) {
            float4 v = emb[i];
            shortx4 w;
            w[0] = (short)f2bf(v.x); w[1] = (short)f2bf(v.y);
            w[2] = (short)f2bf(v.z); w[3] = (short)f2bf(v.w);
            embA[i] = w;
        }
    }
}

// key = node*RR + r (node-major). Saves per-edge bucket rank so fill needs no atomics.
__global__ void hist_k(const int* __restrict__ erow, int* __restrict__ counts,
                       uchar4* __restrict__ rank) {
    int r  = blockIdx.y;
    int i4 = blockIdx.x * 256 + threadIdx.x;
    if (i4 < EE / 4) {
        int4 rw = *(const int4*)(erow + (size_t)r * EE + i4 * 4);
        uchar4 rk;
        rk.x = (unsigned char)atomicAdd(&counts[rw.x * RR + r], 1);
        rk.y = (unsigned char)atomicAdd(&counts[rw.y * RR + r], 1);
        rk.z = (unsigned char)atomicAdd(&counts[rw.z * RR + r], 1);
        rk.w = (unsigned char)atomicAdd(&counts[rw.w * RR + r], 1);
        rank[(size_t)r * (EE / 4) + i4] = rk;
    }
}

__global__ void scanA(const int* __restrict__ c, int* __restrict__ bsum) {
    int b = blockIdx.x, t = threadIdx.x;
    int base = b * SCAN_BLK + t * 16;
    int s = 0;
    #pragma unroll
    for (int i = 0; i < 16; i++) {
        int idx = base + i;
        if (idx < NTOT) s += c[idx];
    }
    __shared__ int sh[256];
    sh[t] = s;
    __syncthreads();
    for (int off = 128; off > 0; off >>= 1) {
        if (t < off) sh[t] += sh[t + off];
        __syncthreads();
    }
    if (t == 0) bsum[b] = sh[0];
}

// scanC derives its own block prefix from raw bsum (scanB folded in).
__global__ void scanC(const int* __restrict__ counts, int* __restrict__ rp,
                      const int* __restrict__ bsum) {
    int b = blockIdx.x, t = threadIdx.x;
    __shared__ int shb[256];
    shb[t] = (t < NSCAN) ? bsum[t] : 0;
    __syncthreads();
    for (int off = 1; off < 256; off <<= 1) {
        int add = (t >= off) ? shb[t - off] : 0;
        __syncthreads();
        shb[t] += add;
        __syncthreads();
    }
    int blockPrefix = (b > 0) ? shb[b - 1] : 0;
    int base = b * SCAN_BLK + t * 16;
    int vals[16];
    int s = 0;
    #pragma unroll
    for (int i = 0; i < 16; i++) {
        int idx = base + i;
        vals[i] = (idx < NTOT) ? counts[idx] : 0;
        s += vals[i];
    }
    __shared__ int sh[256];
    sh[t] = s;
    __syncthreads();
    for (int off = 1; off < 256; off <<= 1) {
        int add = (t >= off) ? sh[t - off] : 0;
        __syncthreads();
        sh[t] += add;
        __syncthreads();
    }
    int run = blockPrefix + sh[t] - s;
    #pragma unroll
    for (int i = 0; i < 16; i++) {
        int idx = base + i;
        if (idx < NTOT) {
            rp[idx] = run;
            run += vals[i];
            if (idx == NTOT - 1) rp[NTOT] = run;
        }
    }
}

// atomic-free placement: pos = rp[key] + saved rank
__global__ void fill_k(const int* __restrict__ erow, const int* __restrict__ ecol,
                       const float* __restrict__ eval, const int* __restrict__ rp,
                       const uchar4* __restrict__ rank, int2* __restrict__ edges) {
    int r  = blockIdx.y;
    int i4 = blockIdx.x * 256 + threadIdx.x;
    if (i4 < EE / 4) {
        int4   rw = *(const int4*)(erow + (size_t)r * EE + i4 * 4);
        int4   cl = *(const int4*)(ecol + (size_t)r * EE + i4 * 4);
        float4 vl = *(const float4*)(eval + (size_t)r * EE + i4 * 4);
        uchar4 rk = rank[(size_t)r * (EE / 4) + i4];
        edges[rp[rw.x * RR + r] + rk.x] = make_int2(cl.x, __float_as_int(vl.x));
        edges[rp[rw.y * RR + r] + rk.y] = make_int2(cl.y, __float_as_int(vl.y));
        edges[rp[rw.z * RR + r] + rk.z] = make_int2(cl.z, __float_as_int(vl.z));
        edges[rp[rw.w * RR + r] + rk.w] = make_int2(cl.w, __float_as_int(vl.w));
    }
}

__device__ __forceinline__ void accum_chunks(float a0[8], float a1[8], float v,
                                             shortx8 c0, shortx8 c1) {
    #pragma unroll
    for (int j = 0; j < 8; j++) {
        a0[j] = fmaf(v, bf2f((unsigned short)c0[j]), a0[j]);
        a1[j] = fmaf(v, bf2f((unsigned short)c1[j]), a1[j]);
    }
}

// Fused layer, register-light. 256 threads = 4 waves, 64-node tile, grid 782.
// Per relation: [branchless gather -> Bt] barrier [MFMA: A-frags direct from L2-resident
// Tf (1 kt prefetch), B from LDS] barrier. No At in LDS; LDS = 16KB Bt.
// Wave w computes D[i in w*32..+32][all 64 n]: acc[2][4].
template<bool FINAL>
__global__ __launch_bounds__(256, 4)
void layer_k(const unsigned short* __restrict__ embIn,
             const unsigned short* __restrict__ Tf,
             const int* __restrict__ rp,
             const int2* __restrict__ eg,
             unsigned short* __restrict__ embOut,
             float* __restrict__ outF)
{
    __shared__ __align__(16) unsigned short Bt[64 * 128];   // 16 KB
    __shared__ float ssred[4][64];

    const int t    = threadIdx.x;
    const int lane = t & 63;
    const int w    = t >> 6;      // 0..3: i block (x32)
    const int colq = lane & 15;
    const int q    = lane >> 4;
    const int n0   = blockIdx.x * NT;
    const int nsub = t >> 3;      // node within pass (0..31)
    const int dgrp = t & 7;       // dim chunks dgrp, dgrp+8

    floatx4 acc[2][4];
    #pragma unroll
    for (int a = 0; a < 2; a++)
        #pragma unroll
        for (int c = 0; c < 4; c++)
            acc[a][c] = (floatx4){0.f, 0.f, 0.f, 0.f};

    #pragma unroll 1
    for (int r = 0; r < RR; r++) {
        // ---- gather (branchless): meta, entries, 4 emb rows, then FMA+pack -> Bt
        int s_[2], c_[2];
        #pragma unroll
        for (int p = 0; p < 2; p++) {
            int n = n0 + p * 32 + nsub;
            bool ok = n < NE;
            int key = (ok ? n : 0) * RR + r;
            int a = rp[key], b2 = rp[key + 1];
            s_[p] = a; c_[p] = ok ? (b2 - a) : 0;
        }
        int   col0[2], col1[2];
        float v0_[2], v1_[2];
        #pragma unroll
        for (int p = 0; p < 2; p++) {
            int2 E0 = eg[s_[p]];          // edges padded; discarded when c==0
            int2 E1 = eg[s_[p] + 1];
            col0[p] = c_[p] > 0 ? E0.x : 0;
            col1[p] = c_[p] > 1 ? E1.x : 0;
            v0_[p]  = c_[p] > 0 ? __int_as_float(E0.y) : 0.f;
            v1_[p]  = c_[p] > 1 ? __int_as_float(E1.y) : 0.f;
        }
        shortx8 m[2][2][2];   // [p][edge][chunk]
        #pragma unroll
        for (int p = 0; p < 2; p++) {
            const unsigned short* r0 = embIn + (size_t)col0[p] * DD + dgrp * 8;
            const unsigned short* r1 = embIn + (size_t)col1[p] * DD + dgrp * 8;
            m[p][0][0] = *(const shortx8*)r0;
            m[p][0][1] = *(const shortx8*)(r0 + 64);
            m[p][1][0] = *(const shortx8*)r1;
            m[p][1][1] = *(const shortx8*)(r1 + 64);
        }
        #pragma unroll
        for (int p = 0; p < 2; p++) {
            float a0[8], a1[8];
            #pragma unroll
            for (int j = 0; j < 8; j++) { a0[j] = 0.f; a1[j] = 0.f; }
            accum_chunks(a0, a1, v0_[p], m[p][0][0], m[p][0][1]);
            accum_chunks(a0, a1, v1_[p], m[p][1][0], m[p][1][1]);
            if (c_[p] > 2) {
                #pragma unroll 1
                for (int k = s_[p] + 2; k < s_[p] + c_[p]; k++) {
                    int2 E = eg[k];
                    float v = __int_as_float(E.y);
                    const unsigned short* rw_ = embIn + (size_t)E.x * DD + dgrp * 8;
                    accum_chunks(a0, a1, v, *(const shortx8*)rw_, *(const shortx8*)(rw_ + 64));
                }
            }
            int nl = p * 32 + nsub;
            shortx8 w0, w1;
            #pragma unroll
            for (int j = 0; j < 8; j++) { w0[j] = (short)f2bf(a0[j]); w1[j] = (short)f2bf(a1[j]); }
            int pc = (dgrp ^ nl) & 7;
            *(shortx8*)&Bt[nl * 128 + pc * 8] = w0;
            *(shortx8*)&Bt[nl * 128 + (8 | pc) * 8] = w1;
        }
        __syncthreads();   // Bt(r) ready

        // ---- MFMA: A-frags from global Tf, 1-kt prefetch; B from Bt
        shortx8 afN[2];
        #pragma unroll
        for (int it2 = 0; it2 < 2; it2++)
            afN[it2] = *(const shortx8*)(Tf + ((((size_t)r * 8 + (w * 2 + it2)) * 4 + 0) * 64 + lane) * 8);
        #pragma unroll 1
        for (int kt = 0; kt < 4; kt++) {
            shortx8 afC[2];
            afC[0] = afN[0]; afC[1] = afN[1];
            if (kt < 3) {
                #pragma unroll
                for (int it2 = 0; it2 < 2; it2++)
                    afN[it2] = *(const shortx8*)(Tf + ((((size_t)r * 8 + (w * 2 + it2)) * 4 + (kt + 1)) * 64 + lane) * 8);
            }
            int lc = kt * 4 + q;
            shortx8 bfr[4];
            #pragma unroll
            for (int c = 0; c < 4; c++) {
                int nl = c * 16 + colq;
                int pc = (lc & 8) | ((lc ^ nl) & 7);
                bfr[c] = *(const shortx8*)&Bt[nl * 128 + pc * 8];
            }
            #pragma unroll
            for (int it2 = 0; it2 < 2; it2++)
                #pragma unroll
                for (int c = 0; c < 4; c++)
                    acc[it2][c] = __builtin_amdgcn_mfma_f32_16x16x32_bf16(afC[it2], bfr[c], acc[it2][c], 0, 0, 0);
        }
        __syncthreads();   // MFMA done with Bt
    }

    // ---- epilogue. D: col=lane&15 -> n, row=q*4+g -> i (within 16x16 tile)
    if (!FINAL) {
        #pragma unroll
        for (int c = 0; c < 4; c++) {
            int n = n0 + c * 16 + colq;
            if (n < NE) {
                #pragma unroll
                for (int it2 = 0; it2 < 2; it2++) {
                    shortx4 wv;
                    #pragma unroll
                    for (int g = 0; g < 4; g++) {
                        float v = acc[it2][c][g];
                        v = v > 0.f ? v : 0.f;
                        wv[g] = (short)f2bf(v);
                    }
                    *(shortx4*)(embOut + ((size_t)n * DD + w * 32 + it2 * 16 + q * 4)) = wv;
                }
            }
        }
    } else {
        #pragma unroll
        for (int c = 0; c < 4; c++) {
            float ss = 0.f;
            #pragma unroll
            for (int it2 = 0; it2 < 2; it2++)
                #pragma unroll
                for (int g = 0; g < 4; g++) {
                    float v = acc[it2][c][g];
                    v = v > 0.f ? v : 0.f;
                    acc[it2][c][g] = v;
                    ss += v * v;
                }
            ss += __shfl_xor(ss, 16, 64);   // reduce over q quads
            ss += __shfl_xor(ss, 32, 64);
            if (q == 0) ssred[w][c * 16 + colq] = ss;
        }
        __syncthreads();
        #pragma unroll
        for (int c = 0; c < 4; c++) {
            int nl = c * 16 + colq;
            float tot = ssred[0][nl] + ssred[1][nl] + ssred[2][nl] + ssred[3][nl];
            float scale = 1.f / fmaxf(sqrtf(tot), 1e-12f);
            int n = n0 + nl;
            if (n < NE) {
                #pragma unroll
                for (int it2 = 0; it2 < 2; it2++) {
                    floatx4 v4;
                    #pragma unroll
                    for (int g = 0; g < 4; g++) v4[g] = acc[it2][c][g] * scale;
                    *(floatx4*)(outF + ((size_t)n * DD + w * 32 + it2 * 16 + q * 4)) = v4;
                }
            }
        }
    }
}

static inline size_t align256(size_t x) { return (x + 255) & ~(size_t)255; }

extern "C" void kernel_launch(void* const* d_in, const int* in_sizes, int n_in,
                              void* d_out, int out_size, void* d_ws, size_t ws_size,
                              hipStream_t stream)
{
    const float* ent_emb   = (const float*)d_in[0];   // [NE, DD] fp32
    const float* rel_trans = (const float*)d_in[1];   // [RR, DD, DD] fp32
    const float* edge_val  = (const float*)d_in[2];   // [RR, EE] fp32
    const int*   edge_row  = (const int*)d_in[3];     // [RR, EE] int32
    const int*   edge_col  = (const int*)d_in[4];     // [RR, EE] int32
    float* out = (float*)d_out;                       // [NE, DD] fp32

    char* ws = (char*)d_ws;
    size_t off = 0;
    int* counts = (int*)(ws + off);  off = align256(off + (size_t)NTOT * 4);
    int* rpf    = (int*)(ws + off);  off = align256(off + ((size_t)NTOT + 1) * 4);
    int* bsum   = (int*)(ws + off);  off = align256(off + 256 * 4);
    uchar4* rank = (uchar4*)(ws + off); off = align256(off + (size_t)NTOT);
    int2* edges = (int2*)(ws + off); off = align256(off + ((size_t)NTOT + 4) * 8);  // +pad
    unsigned short* Tf   = (unsigned short*)(ws + off); off = align256(off + (size_t)RR * DD * DD * 2);
    unsigned short* embA = (unsigned short*)(ws + off); off = align256(off + (size_t)NE * DD * 2);
    unsigned short* embB = (unsigned short*)(ws + off); off = align256(off + (size_t)NE * DD * 2);
    // total ~40 MB

    prep_k<<<ZB + TB + EB, 256, 0, stream>>>(rel_trans, Tf, (const float4*)ent_emb,
                                             (shortx4*)embA, counts);
    dim3 eg_grid((EE / 4 + 255) / 256, RR);
    hist_k<<<eg_grid, 256, 0, stream>>>(edge_row, counts, rank);
    scanA<<<NSCAN, 256, 0, stream>>>(counts, bsum);
    scanC<<<NSCAN, 256, 0, stream>>>(counts, rpf, bsum);
    fill_k<<<eg_grid, 256, 0, stream>>>(edge_row, edge_col, edge_val, rpf, rank, edges);

    int nb = (NE + NT - 1) / NT;  // 782
    layer_k<false><<<nb, 256, 0, stream>>>(embA, Tf, rpf, edges, embB, nullptr);
    layer_k<true ><<<nb, 256, 0, stream>>>(embB, Tf, rpf, edges, nullptr, out);
}